// Round 1
// baseline (10154.609 us; speedup 1.0000x reference)
//
#include <hip/hip_runtime.h>
#include <math.h>

#define BATCH 512
#define MAXLEN 80
#define LATENT 10
#define HID 64
#define NSTEPS 100
#define DT 0.01f

__global__ __launch_bounds__(64) void vae_sde_kernel(
    const float* __restrict__ z_mean, const float* __restrict__ z_log_var,
    const float* __restrict__ W1, const float* __restrict__ b1,
    const float* __restrict__ W2, const float* __restrict__ b2,
    const float* __restrict__ noise, float* __restrict__ out)
{
    __shared__ float sW1[11][HID];
    __shared__ float sb1[HID];
    __shared__ float sW2T[LATENT][HID];
    __shared__ float sb2[LATENT];

    // cooperative LDS fill (64 threads)
    for (int i = threadIdx.x; i < 11 * HID; i += 64) sW1[i >> 6][i & 63] = W1[i];
    sb1[threadIdx.x] = b1[threadIdx.x];
    for (int i = threadIdx.x; i < LATENT * HID; i += 64) {
        int d = i >> 6, j = i & 63;
        sW2T[d][j] = W2[j * LATENT + d];
    }
    if (threadIdx.x < LATENT) sb2[threadIdx.x] = b2[threadIdx.x];
    __syncthreads();

    const int c  = blockIdx.x * 64 + threadIdx.x;   // chain id, 0..40959
    const int l  = c >> 9;                          // position 0..79
    const int bb = c & 511;                         // batch 0..511

    const int base  = (bb * MAXLEN + l) * LATENT;
    const int basep = base - LATENT;                // (bb, l-1)

    float mu[LATENT], inv_sig[LATENT], a0[LATENT], c1v[LATENT], c2v[LATENT];
    float xt[LATENT], errs[LATENT];

    const float sqrt_dt = sqrtf(DT);

    #pragma unroll
    for (int d = 0; d < LATENT; ++d) {
        float zm  = z_mean[base + d];
        float zmp = (l > 0) ? z_mean[basep + d] : 0.0f;
        float m   = zm - zmp;
        float zv  = z_log_var[base + d];
        float zvp = (l > 0) ? z_log_var[basep + d] : 0.0f;
        // stable logaddexp
        float mx  = fmaxf(zv, zvp);
        float sg  = mx + log1pf(expf(-fabsf(zv - zvp)));
        float sd  = expf(0.5f * sg);      // sigma_std
        float var = sd * sd;              // sigma_var

        mu[d]      = m;
        inv_sig[d] = 1.0f / sg;           // precise div, once per chain
        a0[d]      = m * DT;
        c1v[d]     = 0.5f * DT * var;
        c2v[d]     = sd * sqrt_dt;
        xt[d]      = m;                   // scan carry init = mu_l
        errs[d]    = 0.0f;
    }

    // noise[l, s, b, d]
    const float* nptr = noise + (size_t)l * (NSTEPS * BATCH * LATENT) + bb * LATENT;

    float nz[LATENT];
    #pragma unroll
    for (int q = 0; q < 5; ++q) {
        float2 v = *(const float2*)(nptr + 2 * q);
        nz[2 * q] = v.x; nz[2 * q + 1] = v.y;
    }

    #pragma unroll 1
    for (int s = 0; s < NSTEPS; ++s) {
        float cur[LATENT];
        #pragma unroll
        for (int d = 0; d < LATENT; ++d) cur[d] = nz[d];
        if (s + 1 < NSTEPS) {
            const float* np2 = nptr + (size_t)(s + 1) * (BATCH * LATENT);
            #pragma unroll
            for (int q = 0; q < 5; ++q) {
                float2 v = *(const float2*)(np2 + 2 * q);
                nz[2 * q] = v.x; nz[2 * q + 1] = v.y;
            }
        }

        // h = b1
        float h[HID];
        #pragma unroll
        for (int j = 0; j < HID; j += 4) {
            float4 v = *(const float4*)&sb1[j];
            h[j] = v.x; h[j + 1] = v.y; h[j + 2] = v.z; h[j + 3] = v.w;
        }
        // h += xt @ W1[0:10]
        #pragma unroll
        for (int k = 0; k < LATENT; ++k) {
            float xk = xt[k];
            #pragma unroll
            for (int j = 0; j < HID; j += 4) {
                float4 w = *(const float4*)&sW1[k][j];
                h[j]     = fmaf(xk, w.x, h[j]);
                h[j + 1] = fmaf(xk, w.y, h[j + 1]);
                h[j + 2] = fmaf(xk, w.z, h[j + 2]);
                h[j + 3] = fmaf(xk, w.w, h[j + 3]);
            }
        }
        // t feature + relu
        float tt = (float)(l + s) * DT;
        #pragma unroll
        for (int j = 0; j < HID; j += 4) {
            float4 w = *(const float4*)&sW1[10][j];
            h[j]     = fmaxf(fmaf(tt, w.x, h[j]),     0.0f);
            h[j + 1] = fmaxf(fmaf(tt, w.y, h[j + 1]), 0.0f);
            h[j + 2] = fmaxf(fmaf(tt, w.z, h[j + 2]), 0.0f);
            h[j + 3] = fmaxf(fmaf(tt, w.w, h[j + 3]), 0.0f);
        }
        // score = h @ W2 + b2 ; err ; xt update
        #pragma unroll
        for (int d = 0; d < LATENT; ++d) {
            float acc = sb2[d];
            #pragma unroll
            for (int j = 0; j < HID; j += 4) {
                float4 w = *(const float4*)&sW2T[d][j];
                acc = fmaf(h[j],     w.x, acc);
                acc = fmaf(h[j + 1], w.y, acc);
                acc = fmaf(h[j + 2], w.z, acc);
                acc = fmaf(h[j + 3], w.w, acc);
            }
            float ld = (mu[d] - xt[d]) * inv_sig[d];   // logdx
            float df = ld - acc;
            errs[d]  = fmaf(df, df, errs[d]);
            xt[d]    = xt[d] + a0[d] + c1v[d] * acc + c2v[d] * cur[d];
        }
    }

    float* o0 = out + base;                           // sequence
    float* o1 = out + (BATCH * MAXLEN * LATENT) + base; // score_error
    #pragma unroll
    for (int d = 0; d < LATENT; ++d) {
        o0[d] = xt[d];
        o1[d] = errs[d] * (1.0f / NSTEPS);
    }
}

extern "C" void kernel_launch(void* const* d_in, const int* in_sizes, int n_in,
                              void* d_out, int out_size, void* d_ws, size_t ws_size,
                              hipStream_t stream) {
    const float* z_mean    = (const float*)d_in[0];
    const float* z_log_var = (const float*)d_in[1];
    const float* W1 = (const float*)d_in[2];
    const float* b1 = (const float*)d_in[3];
    const float* W2 = (const float*)d_in[4];
    const float* b2 = (const float*)d_in[5];
    const float* noise = (const float*)d_in[6];
    float* out = (float*)d_out;

    vae_sde_kernel<<<dim3(640), dim3(64), 0, stream>>>(
        z_mean, z_log_var, W1, b1, W2, b2, noise, out);
}

// Round 2
// 9916.081 us; speedup vs baseline: 1.0241x; 1.0241x over previous
//
#include <hip/hip_runtime.h>
#include <math.h>

#define BATCH 512
#define MAXLEN 80
#define LATENT 10
#define HID 64
#define NSTEPS 100
#define DT 0.01f

__global__ __launch_bounds__(64) void vae_sde_kernel(
    const float* __restrict__ z_mean, const float* __restrict__ z_log_var,
    const float* __restrict__ W1, const float* __restrict__ b1,
    const float* __restrict__ W2, const float* __restrict__ b2,
    const float* __restrict__ noise, float* __restrict__ out)
{
    __shared__ float sW1[11][HID];   // row k = input feature k
    __shared__ float sb1[HID];
    __shared__ float sW2T[LATENT][HID];

    for (int i = threadIdx.x; i < 11 * HID; i += 64) sW1[i >> 6][i & 63] = W1[i];
    sb1[threadIdx.x] = b1[threadIdx.x];
    for (int i = threadIdx.x; i < LATENT * HID; i += 64) {
        int d = i >> 6, j = i & 63;
        sW2T[d][j] = W2[j * LATENT + d];
    }
    __syncthreads();

    const int c  = blockIdx.x * 64 + threadIdx.x;   // chain id
    const int l  = c >> 9;                          // position 0..79
    const int bb = c & 511;                         // batch 0..511

    const int base  = (bb * MAXLEN + l) * LATENT;
    const int basep = base - LATENT;

    float mu[LATENT], inv_sig[LATENT], a0[LATENT], c1v[LATENT], c2v[LATENT];
    float xt[LATENT], errs[LATENT], rb2[LATENT];

    const float sqrt_dt = sqrtf(DT);

    #pragma unroll
    for (int d = 0; d < LATENT; ++d) {
        float zm  = z_mean[base + d];
        float zmp = (l > 0) ? z_mean[basep + d] : 0.0f;
        float m   = zm - zmp;
        float zv  = z_log_var[base + d];
        float zvp = (l > 0) ? z_log_var[basep + d] : 0.0f;
        float mx  = fmaxf(zv, zvp);
        float sg  = mx + log1pf(expf(-fabsf(zv - zvp)));
        float sd  = expf(0.5f * sg);
        float var = sd * sd;

        mu[d]      = m;
        inv_sig[d] = 1.0f / sg;
        a0[d]      = m * DT;
        c1v[d]     = 0.5f * DT * var;
        c2v[d]     = sd * sqrt_dt;
        xt[d]      = m;
        errs[d]    = 0.0f;
        rb2[d]     = b2[d];
    }

    const float* nptr = noise + (size_t)l * (NSTEPS * BATCH * LATENT) + bb * LATENT;

    float nz[LATENT];
    #pragma unroll
    for (int q = 0; q < 5; ++q) {
        float2 v = *(const float2*)(nptr + 2 * q);
        nz[2 * q] = v.x; nz[2 * q + 1] = v.y;
    }

    #pragma unroll 1
    for (int s = 0; s < NSTEPS; ++s) {
        float cur[LATENT];
        #pragma unroll
        for (int d = 0; d < LATENT; ++d) cur[d] = nz[d];
        if (s + 1 < NSTEPS) {
            const float* np2 = nptr + (size_t)(s + 1) * (BATCH * LATENT);
            #pragma unroll
            for (int q = 0; q < 5; ++q) {
                float2 v = *(const float2*)(np2 + 2 * q);
                nz[2 * q] = v.x; nz[2 * q + 1] = v.y;
            }
        }

        const float tt = (float)(l + s) * DT;

        // score accumulators
        float acc[LATENT];
        #pragma unroll
        for (int d = 0; d < LATENT; ++d) acc[d] = rb2[d];

        // process HID in chunks of 16: build h-chunk, fold into acc, discard
        #pragma unroll
        for (int j0 = 0; j0 < HID; j0 += 16) {
            float hh[16];
            #pragma unroll
            for (int q = 0; q < 4; ++q) {
                float4 v = *(const float4*)&sb1[j0 + 4 * q];
                hh[4 * q] = v.x; hh[4 * q + 1] = v.y; hh[4 * q + 2] = v.z; hh[4 * q + 3] = v.w;
            }
            #pragma unroll
            for (int k = 0; k < LATENT; ++k) {
                float xk = xt[k];
                #pragma unroll
                for (int q = 0; q < 4; ++q) {
                    float4 w = *(const float4*)&sW1[k][j0 + 4 * q];
                    hh[4 * q]     = fmaf(xk, w.x, hh[4 * q]);
                    hh[4 * q + 1] = fmaf(xk, w.y, hh[4 * q + 1]);
                    hh[4 * q + 2] = fmaf(xk, w.z, hh[4 * q + 2]);
                    hh[4 * q + 3] = fmaf(xk, w.w, hh[4 * q + 3]);
                }
            }
            #pragma unroll
            for (int q = 0; q < 4; ++q) {
                float4 w = *(const float4*)&sW1[10][j0 + 4 * q];
                hh[4 * q]     = fmaxf(fmaf(tt, w.x, hh[4 * q]),     0.0f);
                hh[4 * q + 1] = fmaxf(fmaf(tt, w.y, hh[4 * q + 1]), 0.0f);
                hh[4 * q + 2] = fmaxf(fmaf(tt, w.z, hh[4 * q + 2]), 0.0f);
                hh[4 * q + 3] = fmaxf(fmaf(tt, w.w, hh[4 * q + 3]), 0.0f);
            }
            #pragma unroll
            for (int d = 0; d < LATENT; ++d) {
                float a = acc[d];
                #pragma unroll
                for (int q = 0; q < 4; ++q) {
                    float4 w = *(const float4*)&sW2T[d][j0 + 4 * q];
                    a = fmaf(hh[4 * q],     w.x, a);
                    a = fmaf(hh[4 * q + 1], w.y, a);
                    a = fmaf(hh[4 * q + 2], w.z, a);
                    a = fmaf(hh[4 * q + 3], w.w, a);
                }
                acc[d] = a;
            }
        }

        // err + xt update
        #pragma unroll
        for (int d = 0; d < LATENT; ++d) {
            float ld = (mu[d] - xt[d]) * inv_sig[d];
            float df = ld - acc[d];
            errs[d]  = fmaf(df, df, errs[d]);
            xt[d]    = xt[d] + a0[d] + c1v[d] * acc[d] + c2v[d] * cur[d];
        }
    }

    float* o0 = out + base;
    float* o1 = out + (BATCH * MAXLEN * LATENT) + base;
    #pragma unroll
    for (int d = 0; d < LATENT; ++d) {
        o0[d] = xt[d];
        o1[d] = errs[d] * (1.0f / NSTEPS);
    }
}

extern "C" void kernel_launch(void* const* d_in, const int* in_sizes, int n_in,
                              void* d_out, int out_size, void* d_ws, size_t ws_size,
                              hipStream_t stream) {
    const float* z_mean    = (const float*)d_in[0];
    const float* z_log_var = (const float*)d_in[1];
    const float* W1 = (const float*)d_in[2];
    const float* b1 = (const float*)d_in[3];
    const float* W2 = (const float*)d_in[4];
    const float* b2 = (const float*)d_in[5];
    const float* noise = (const float*)d_in[6];
    float* out = (float*)d_out;

    vae_sde_kernel<<<dim3(640), dim3(64), 0, stream>>>(
        z_mean, z_log_var, W1, b1, W2, b2, noise, out);
}